// Round 4
// baseline (25585.876 us; speedup 1.0000x reference)
//
#include <hip/hip_runtime.h>

// Problem constants
#define Bn   512
#define Tn   1024
#define Fn   64
#define Hn   512
#define NB1  128                 // LSTM1 blocks: 8 rt x 16 utp
#define NB2  16                  // LSTM2 blocks: 8 rt x 2 u2
#define NBLK (NB1 + NB2)
#define TRIES (1L << 22)         // safety valve for poll loops

typedef short bf16x8 __attribute__((ext_vector_type(8)));
typedef float f32x4  __attribute__((ext_vector_type(4)));
typedef unsigned int u32;
typedef unsigned long long u64;

__device__ __forceinline__ short f2bf(float f) {
    union { float f; unsigned u; } v; v.f = f;
    unsigned r = (v.u + 0x7FFFu + ((v.u >> 16) & 1u)) >> 16;  // RNE
    return (short)(unsigned short)r;
}
__device__ __forceinline__ float sigm(float x) { return 1.f / (1.f + __expf(-x)); }
__device__ __forceinline__ float tanh_(float x) { return 2.f / (1.f + __expf(-2.f * x)) - 1.f; }

__device__ __forceinline__ bf16x8 cvt8v(float4 v0, float4 v1) {
    bf16x8 a;
    a[0] = f2bf(v0.x); a[1] = f2bf(v0.y); a[2] = f2bf(v0.z); a[3] = f2bf(v0.w);
    a[4] = f2bf(v1.x); a[5] = f2bf(v1.y); a[6] = f2bf(v1.z); a[7] = f2bf(v1.w);
    return a;
}

// -------- MALL-coherent primitives (relaxed agent scope; bypass per-XCD L2) --------
__device__ __forceinline__ u64 ald64(const u32* p) {
    return __hip_atomic_load((const u64*)p, __ATOMIC_RELAXED, __HIP_MEMORY_SCOPE_AGENT);
}
__device__ __forceinline__ void ast4(u32* p, u32 v) {
    __hip_atomic_store(p, v, __ATOMIC_RELAXED, __HIP_MEMORY_SCOPE_AGENT);
}
__device__ __forceinline__ int aldi(const int* p) {
    return __hip_atomic_load(p, __ATOMIC_RELAXED, __HIP_MEMORY_SCOPE_AGENT);
}
__device__ __forceinline__ void asti(int* p, int v) {
    __hip_atomic_store(p, v, __ATOMIC_RELAXED, __HIP_MEMORY_SCOPE_AGENT);
}

// ---- tagged-word exchange: word = (bf16 value << 16) | (step tag & 0xFFFF) ----
// The DATA carries its own validity: no producer barrier, no flags, no drain.
// A chunk = 8 consecutive words (32 B) = one MFMA A-fragment for one row.
struct C4 { u64 v0, v1, v2, v3; };
__device__ __forceinline__ C4 ld_chunk(const u32* p) {
    C4 c; c.v0 = ald64(p); c.v1 = ald64(p + 2); c.v2 = ald64(p + 4); c.v3 = ald64(p + 6);
    return c;
}
__device__ __forceinline__ int tag_ok(const C4& c, u64 tp) {
    const u64 M = 0x0000FFFF0000FFFFull;
    return (int)(((c.v0 & M) == tp) & ((c.v1 & M) == tp) & ((c.v2 & M) == tp) & ((c.v3 & M) == tp));
}
__device__ __forceinline__ bf16x8 packA(const C4& c) {
    bf16x8 a;
    a[0] = (short)(c.v0 >> 16); a[1] = (short)(c.v0 >> 48);
    a[2] = (short)(c.v1 >> 16); a[3] = (short)(c.v1 >> 48);
    a[4] = (short)(c.v2 >> 16); a[5] = (short)(c.v2 >> 48);
    a[6] = (short)(c.v3 >> 16); a[7] = (short)(c.v3 >> 48);
    return a;
}
__device__ __forceinline__ void await_chunk(C4& c, const u32* p, u64 tp) {
    long tries = 0;
    while (!__all(tag_ok(c, tp))) {          // first check uses the pre-issued load
        if (++tries > TRIES) break;          // broken logic -> terminate, tests fail loudly
        __builtin_amdgcn_s_sleep(1);
        c = ld_chunk(p);
    }
}

// ---------------- prepack ----------------
// w1f: [ut 32][kb 18][gate 4][n 16][kk 32]  (gcol = gate*512 + ut*16 + n, k = kb*32+kk)
// w2f: [ut4 4][kb 18][gate 4][n 16][kk 32]  (gcol = gate*64 + ut4*16 + n)
// h1x: u32[2][512][512] tagged words; c1x: u32[3][512][512]; h2x: u32[2][512][64]
__global__ void prep_kernel(const float* __restrict__ Wih1, const float* __restrict__ Whh1,
                            const float* __restrict__ Wih2, const float* __restrict__ Whh2,
                            const float* __restrict__ bih1, const float* __restrict__ bhh1,
                            const float* __restrict__ bih2, const float* __restrict__ bhh2,
                            u32* __restrict__ h1x, u32* __restrict__ c1x, u32* __restrict__ h2x,
                            short* __restrict__ w1f, short* __restrict__ w2f,
                            float* __restrict__ bs1, float* __restrict__ bs2,
                            int* __restrict__ l2f) {
    const int i0 = blockIdx.x * blockDim.x + threadIdx.x;
    const int stride = gridDim.x * blockDim.x;
    for (int i = i0; i < 128; i += stride) l2f[i] = 0;
    for (int i = i0; i < 2 * Bn * Hn; i += stride) h1x[i] = 0u;   // value 0, tag 0
    for (int i = i0; i < 3 * Bn * Hn; i += stride) c1x[i] = 0u;
    for (int i = i0; i < 2 * Bn * Fn; i += stride) h2x[i] = 0u;
    for (int i = i0; i < 2048 * 576; i += stride) {
        int kk = i & 31, n = (i >> 5) & 15, ct = (i >> 9) & 3;
        int r = i >> 11; int kb = r % 18; int ut = r / 18;
        int gcol = ct * 512 + ut * 16 + n;
        int k = kb * 32 + kk;
        float v = (k < 64) ? Wih1[gcol * 64 + k] : Whh1[gcol * 512 + (k - 64)];
        w1f[i] = f2bf(v);
    }
    for (int i = i0; i < 256 * 576; i += stride) {
        int kk = i & 31, n = (i >> 5) & 15, ct = (i >> 9) & 3;
        int r = i >> 11; int kb = r % 18; int ut4 = r / 18;
        int gcol = ct * 64 + ut4 * 16 + n;
        int k = kb * 32 + kk;
        float v = (k < 512) ? Wih2[gcol * 512 + k] : Whh2[gcol * 64 + (k - 512)];
        w2f[i] = f2bf(v);
    }
    for (int i = i0; i < 2048; i += stride) bs1[i] = bih1[i] + bhh1[i];
    for (int i = i0; i < 256;  i += stride) bs2[i] = bih2[i] + bhh2[i];
}

// ---------------- main persistent kernel ----------------
// 144 blocks x 256 threads (4 waves), 1 block/CU. Tagged-word exchange:
//   writer at step t stores tag t+1; reader at step s of h(s-1) expects tag s.
// Skew safety: h1x (L1<->L1 peers) and h2x (L2 pair) are MUTUAL exchanges ->
//   skew <= 1 step -> 2-parity buffers race-free (a block can only overwrite a
//   parity after consuming ALL peers' next-step tags, which implies every peer
//   finished reading the parity being overwritten). c1x (L1 -> L2, one-way) is
//   TRIPLE-buffered and guarded by a lazy L2 progress flag polled 2 steps in
//   arrears (off the critical path in steady state).
// Register economy: 8 of 16 recurrent k-blocks' weights in VGPRs; the other 8
//   stream from (XCD-local, L2-resident) w1f/w2f each step. This funds the
//   128-VGPR chunk staging that keeps all tag-checked loads deeply pipelined.
__global__ __launch_bounds__(256, 1) void lstm_kernel(
    const float* __restrict__ data,
    const short* __restrict__ w1f, const float* __restrict__ bs1,
    const short* __restrict__ w2f, const float* __restrict__ bs2,
    u32* __restrict__ h1x, u32* __restrict__ c1x, u32* __restrict__ h2x,
    float* __restrict__ out, int* __restrict__ l2flags) {
    const int tid = threadIdx.x;
    const int lane = tid & 63, wv = tid >> 6;
    const int n = lane & 15, q = lane >> 4;
    const int wvr = wv & 1, wvc = wv >> 1;
    const int bid = blockIdx.x;
    const f32x4 Z4 = {0.f, 0.f, 0.f, 0.f};

    if (bid < NB1) {
        // ---------------- LSTM1: no barriers, no flags, store-and-go ----------------
        const int rt = bid >> 4, utp = bid & 15;
        const int ut = utp * 2 + wvc;
        const int rowbase = rt * 64 + wvr * 32;
        const int ucol = ut * 16 + n;
        int* l2f = l2flags + rt * 16;
        const float bi_ = bs1[ucol], bf_ = bs1[512 + ucol], bg_ = bs1[1024 + ucol], bo_ = bs1[1536 + ucol];
        const short* wbase = w1f + ut * 36864 + n * 32 + q * 8;
        const int r0 = rowbase + n, r1 = rowbase + 16 + n;

        // register-resident recurrent weights: h-kb 8..15 (w1f kb' 10..17)
        bf16x8 wr[8][4];
#pragma unroll
        for (int kb8 = 0; kb8 < 8; ++kb8)
#pragma unroll
            for (int g = 0; g < 4; ++g)
                wr[kb8][g] = *(const bf16x8*)(wbase + ((kb8 + 10) * 4 + g) * 512);

        f32x4 c1f[2]; c1f[0] = Z4; c1f[1] = Z4;

        for (int t = 0; t < Tn; ++t) {
            const u32* hr = h1x + (t & 1) * (Bn * Hn);
            u32* hw = h1x + ((t + 1) & 1) * (Bn * Hn);
            u32* cw = c1x + (t % 3) * (Bn * Hn);
            const u32 etag = (u32)(t & 0xFFFF);              // expected tag for h(t-1)
            const u64 tp = ((u64)etag << 32) | etag;
            const u32 wtag = (u32)((t + 1) & 0xFFFF);        // tag we publish

            f32x4 acc[2][4];
#pragma unroll
            for (int a = 0; a < 2; ++a)
#pragma unroll
                for (int g = 0; g < 4; ++g) acc[a][g] = Z4;

            // --- issue oldest loads first: x data + x-part streamed weights ---
            const float* x0 = data + (size_t)r0 * 65536 + t * 64;
            const float* x1 = data + (size_t)r1 * 65536 + t * 64;
            float4 xv0[2][2], xv1[2][2];
#pragma unroll
            for (int kb = 0; kb < 2; ++kb) {
                xv0[kb][0] = *(const float4*)(x0 + kb * 32 + q * 8);
                xv0[kb][1] = *(const float4*)(x0 + kb * 32 + q * 8 + 4);
                xv1[kb][0] = *(const float4*)(x1 + kb * 32 + q * 8);
                xv1[kb][1] = *(const float4*)(x1 + kb * 32 + q * 8 + 4);
            }
            bf16x8 bx[2][4];
#pragma unroll
            for (int kb = 0; kb < 2; ++kb)
#pragma unroll
                for (int g = 0; g < 4; ++g)
                    bx[kb][g] = *(const bf16x8*)(wbase + (kb * 4 + g) * 512);

            // --- issue r0 chunk loads, batch 1 (reg-weight kbs processed first) ---
            C4 S[16];
#pragma unroll
            for (int i = 0; i < 8; ++i) {
                const int kb = i + 8;
                S[kb] = ld_chunk(hr + r0 * 512 + kb * 32 + q * 8);
            }

            // --- x-part MFMAs (waits only on the x/bx loads: they are oldest) ---
#pragma unroll
            for (int kb = 0; kb < 2; ++kb) {
                const bf16x8 a0 = cvt8v(xv0[kb][0], xv0[kb][1]);
                const bf16x8 a1 = cvt8v(xv1[kb][0], xv1[kb][1]);
#pragma unroll
                for (int g = 0; g < 4; ++g) {
                    acc[0][g] = __builtin_amdgcn_mfma_f32_16x16x32_bf16(a0, bx[kb][g], acc[0][g], 0, 0, 0);
                    acc[1][g] = __builtin_amdgcn_mfma_f32_16x16x32_bf16(a1, bx[kb][g], acc[1][g], 0, 0, 0);
                }
            }

            // --- issue r0 chunk loads, batch 2 ---
#pragma unroll
            for (int i = 0; i < 8; ++i) {
                const int kb = i;
                S[kb] = ld_chunk(hr + r0 * 512 + kb * 32 + q * 8);
            }

            // --- r0 pass: validate -> pack -> reissue r1 into same slot -> MFMA ---
#pragma unroll
            for (int i = 0; i < 16; ++i) {
                const int kb = (i + 8) & 15;
                await_chunk(S[kb], hr + r0 * 512 + kb * 32 + q * 8, tp);
                const bf16x8 a0 = packA(S[kb]);
                S[kb] = ld_chunk(hr + r1 * 512 + kb * 32 + q * 8);   // prefetch r1 pass
                if (kb >= 8) {
#pragma unroll
                    for (int g = 0; g < 4; ++g)
                        acc[0][g] = __builtin_amdgcn_mfma_f32_16x16x32_bf16(a0, wr[kb - 8][g], acc[0][g], 0, 0, 0);
                } else {
#pragma unroll
                    for (int g = 0; g < 4; ++g) {
                        const bf16x8 b = *(const bf16x8*)(wbase + ((kb + 2) * 4 + g) * 512);
                        acc[0][g] = __builtin_amdgcn_mfma_f32_16x16x32_bf16(a0, b, acc[0][g], 0, 0, 0);
                    }
                }
            }
            // --- r1 pass ---
#pragma unroll
            for (int i = 0; i < 16; ++i) {
                const int kb = (i + 8) & 15;
                await_chunk(S[kb], hr + r1 * 512 + kb * 32 + q * 8, tp);
                const bf16x8 a1 = packA(S[kb]);
                if (kb >= 8) {
#pragma unroll
                    for (int g = 0; g < 4; ++g)
                        acc[1][g] = __builtin_amdgcn_mfma_f32_16x16x32_bf16(a1, wr[kb - 8][g], acc[1][g], 0, 0, 0);
                } else {
#pragma unroll
                    for (int g = 0; g < 4; ++g) {
                        const bf16x8 b = *(const bf16x8*)(wbase + ((kb + 2) * 4 + g) * 512);
                        acc[1][g] = __builtin_amdgcn_mfma_f32_16x16x32_bf16(a1, b, acc[1][g], 0, 0, 0);
                    }
                }
            }

            // --- c1x WAR guard (triple buffer; 2 steps of slack; rarely blocks) ---
            if (t >= 3) {
                long s2 = 0;
                while (aldi(l2f + 0) < t - 2 || aldi(l2f + 1) < t - 2) {
                    if (++s2 > TRIES) break;
                    __builtin_amdgcn_s_sleep(1);
                }
            }

            // --- epilogue: compute, store tagged words, and GO (no barrier) ---
#pragma unroll
            for (int rt16 = 0; rt16 < 2; ++rt16) {
#pragma unroll
                for (int r = 0; r < 4; ++r) {
                    const float xi = acc[rt16][0][r] + bi_;
                    const float xf = acc[rt16][1][r] + bf_;
                    const float xg = acc[rt16][2][r] + bg_;
                    const float xo = acc[rt16][3][r] + bo_;
                    const float ii = sigm(xi), ff = sigm(xf), gg = tanh_(xg), oo = sigm(xo);
                    const float c = ff * c1f[rt16][r] + ii * gg;
                    c1f[rt16][r] = c;
                    const float h = oo * tanh_(c);
                    const int row = rowbase + rt16 * 16 + q * 4 + r;
                    ast4(hw + row * 512 + ucol, ((u32)(unsigned short)f2bf(h) << 16) | wtag);
                    ast4(cw + row * 512 + ucol, ((u32)(unsigned short)f2bf(c) << 16) | wtag);
                }
            }
        }
    } else {
        // ---------------- LSTM2 ----------------
        const int b2 = bid - NB1;
        const int rt2 = b2 >> 1, u2 = b2 & 1;
        const int ut4 = u2 * 2 + wvc;
        const int rowbase = rt2 * 64 + wvr * 32;
        const int ucol = ut4 * 16 + n;
        int* l2f = l2flags + rt2 * 16;
        const float bi_ = bs2[ucol], bf_ = bs2[64 + ucol], bg_ = bs2[128 + ucol], bo_ = bs2[192 + ucol];
        const short* wbase = w2f + ut4 * 36864 + n * 32 + q * 8;
        const int r0 = rowbase + n, r1 = rowbase + 16 + n;

        // register-resident weights: c1-kb 8..15 (w2f kb' 8..15)
        bf16x8 wr[8][4];
#pragma unroll
        for (int kb8 = 0; kb8 < 8; ++kb8)
#pragma unroll
            for (int g = 0; g < 4; ++g)
                wr[kb8][g] = *(const bf16x8*)(wbase + ((kb8 + 8) * 4 + g) * 512);

        f32x4 c2f[2]; c2f[0] = Z4; c2f[1] = Z4;

        for (int t = 0; t < Tn; ++t) {
            const u32* cr = c1x + (t % 3) * (Bn * Hn);
            const u32* h2r = h2x + (t & 1) * (Bn * Fn);
            u32* h2w = h2x + ((t + 1) & 1) * (Bn * Fn);
            const u32 ctag = (u32)((t + 1) & 0xFFFF);        // c1(t) carries tag t+1
            const u64 tpc = ((u64)ctag << 32) | ctag;
            const u32 htag = (u32)(t & 0xFFFF);              // h2(t-1) carries tag t
            const u64 tph = ((u64)htag << 32) | htag;

            f32x4 acc[2][4];
#pragma unroll
            for (int a = 0; a < 2; ++a)
#pragma unroll
                for (int g = 0; g < 4; ++g) acc[a][g] = Z4;

            // issue h2 chunks (both rows) + c1 r0 chunks
            C4 HS[2][2];
#pragma unroll
            for (int kb2 = 0; kb2 < 2; ++kb2) {
                HS[kb2][0] = ld_chunk(h2r + r0 * 64 + kb2 * 32 + q * 8);
                HS[kb2][1] = ld_chunk(h2r + r1 * 64 + kb2 * 32 + q * 8);
            }
            C4 S[16];
#pragma unroll
            for (int i = 0; i < 16; ++i) {
                const int kb = (i + 8) & 15;
                S[kb] = ld_chunk(cr + r0 * 512 + kb * 32 + q * 8);
            }

            // c1 r0 pass (reissue r1), then r1 pass
#pragma unroll
            for (int i = 0; i < 16; ++i) {
                const int kb = (i + 8) & 15;
                await_chunk(S[kb], cr + r0 * 512 + kb * 32 + q * 8, tpc);
                const bf16x8 a0 = packA(S[kb]);
                S[kb] = ld_chunk(cr + r1 * 512 + kb * 32 + q * 8);
                if (kb >= 8) {
#pragma unroll
                    for (int g = 0; g < 4; ++g)
                        acc[0][g] = __builtin_amdgcn_mfma_f32_16x16x32_bf16(a0, wr[kb - 8][g], acc[0][g], 0, 0, 0);
                } else {
#pragma unroll
                    for (int g = 0; g < 4; ++g) {
                        const bf16x8 b = *(const bf16x8*)(wbase + (kb * 4 + g) * 512);
                        acc[0][g] = __builtin_amdgcn_mfma_f32_16x16x32_bf16(a0, b, acc[0][g], 0, 0, 0);
                    }
                }
            }
#pragma unroll
            for (int i = 0; i < 16; ++i) {
                const int kb = (i + 8) & 15;
                await_chunk(S[kb], cr + r1 * 512 + kb * 32 + q * 8, tpc);
                const bf16x8 a1 = packA(S[kb]);
                if (kb >= 8) {
#pragma unroll
                    for (int g = 0; g < 4; ++g)
                        acc[1][g] = __builtin_amdgcn_mfma_f32_16x16x32_bf16(a1, wr[kb - 8][g], acc[1][g], 0, 0, 0);
                } else {
#pragma unroll
                    for (int g = 0; g < 4; ++g) {
                        const bf16x8 b = *(const bf16x8*)(wbase + (kb * 4 + g) * 512);
                        acc[1][g] = __builtin_amdgcn_mfma_f32_16x16x32_bf16(a1, b, acc[1][g], 0, 0, 0);
                    }
                }
            }

            // h2 tail (kb' 16,17 streamed weights)
#pragma unroll
            for (int kb2 = 0; kb2 < 2; ++kb2) {
                await_chunk(HS[kb2][0], h2r + r0 * 64 + kb2 * 32 + q * 8, tph);
                await_chunk(HS[kb2][1], h2r + r1 * 64 + kb2 * 32 + q * 8, tph);
                const bf16x8 a0 = packA(HS[kb2][0]);
                const bf16x8 a1 = packA(HS[kb2][1]);
#pragma unroll
                for (int g = 0; g < 4; ++g) {
                    const bf16x8 b = *(const bf16x8*)(wbase + ((16 + kb2) * 4 + g) * 512);
                    acc[0][g] = __builtin_amdgcn_mfma_f32_16x16x32_bf16(a0, b, acc[0][g], 0, 0, 0);
                    acc[1][g] = __builtin_amdgcn_mfma_f32_16x16x32_bf16(a1, b, acc[1][g], 0, 0, 0);
                }
            }

            // epilogue
            const u32 wtag = (u32)((t + 1) & 0xFFFF);
#pragma unroll
            for (int rt16 = 0; rt16 < 2; ++rt16) {
#pragma unroll
                for (int r = 0; r < 4; ++r) {
                    const float xi = acc[rt16][0][r] + bi_;
                    const float xf = acc[rt16][1][r] + bf_;
                    const float xg = acc[rt16][2][r] + bg_;
                    const float xo = acc[rt16][3][r] + bo_;
                    const float ii = sigm(xi), ff = sigm(xf), gg = tanh_(xg), oo = sigm(xo);
                    const float c = ff * c2f[rt16][r] + ii * gg;
                    c2f[rt16][r] = c;
                    const float h = oo * tanh_(c);
                    const int row = rowbase + rt16 * 16 + q * 4 + r;
                    out[(size_t)row * 65536 + (size_t)t * 64 + ucol] = c;  // output is c2
                    ast4(h2w + row * 64 + ucol, ((u32)(unsigned short)f2bf(h) << 16) | wtag);
                }
            }
            // progress flag for L1's c1x WAR guard (c1 reads are complete here).
            __syncthreads();
            if (tid == 0) asti(l2f + u2, t + 1);
        }
    }
}

extern "C" void kernel_launch(void* const* d_in, const int* in_sizes, int n_in,
                              void* d_out, int out_size, void* d_ws, size_t ws_size,
                              hipStream_t stream) {
    const float* data = (const float*)d_in[0];
    const float* Wih1 = (const float*)d_in[1];
    const float* Whh1 = (const float*)d_in[2];
    const float* bih1 = (const float*)d_in[3];
    const float* bhh1 = (const float*)d_in[4];
    const float* Wih2 = (const float*)d_in[5];
    const float* Whh2 = (const float*)d_in[6];
    const float* bih2 = (const float*)d_in[7];
    const float* bhh2 = (const float*)d_in[8];
    float* out = (float*)d_out;

    char* w = (char*)d_ws;
    u32* h1x = (u32*)(w + 0);               // 2*512*512*4 = 2,097,152
    u32* c1x = (u32*)(w + 2097152);         // 3*512*512*4 = 3,145,728
    u32* h2x = (u32*)(w + 5242880);         // 2*512*64*4  =   262,144
    short* w1f = (short*)(w + 5505024);     // 2048*576*2  = 2,359,296
    short* w2f = (short*)(w + 7864320);     // 256*576*2   =   294,912
    float* bs1 = (float*)(w + 8159232);     // 8,192
    float* bs2 = (float*)(w + 8167424);     // 1,024
    int* l2f  = (int*)(w + 8168448);        // 512 B (8 groups x 16 ints)

    hipLaunchKernelGGL(prep_kernel, dim3(1024), dim3(256), 0, stream,
                       Wih1, Whh1, Wih2, Whh2, bih1, bhh1, bih2, bhh2,
                       h1x, c1x, h2x, w1f, w2f, bs1, bs2, l2f);

    hipLaunchKernelGGL(lstm_kernel, dim3(NBLK), dim3(256), 0, stream,
                       data, w1f, bs1, w2f, bs2, h1x, c1x, h2x, out, l2f);
}

// Round 5
// 22148.683 us; speedup vs baseline: 1.1552x; 1.1552x over previous
//
#include <hip/hip_runtime.h>

// Problem constants
#define Bn   512
#define Tn   1024
#define Fn   64
#define Hn   512
#define NB1  128                 // LSTM1 blocks: 8 rt x 16 utp
#define NB2  16                  // LSTM2 blocks: 8 rt x 2 u2
#define NBLK (NB1 + NB2)
#define TRIES (1L << 22)

typedef short bf16x8 __attribute__((ext_vector_type(8)));
typedef float f32x4  __attribute__((ext_vector_type(4)));

__device__ __forceinline__ short f2bf(float f) {
    union { float f; unsigned u; } v; v.f = f;
    unsigned r = (v.u + 0x7FFFu + ((v.u >> 16) & 1u)) >> 16;  // RNE
    return (short)(unsigned short)r;
}
__device__ __forceinline__ float sigm(float x) { return 1.f / (1.f + __expf(-x)); }
__device__ __forceinline__ float tanh_(float x) { return 2.f / (1.f + __expf(-2.f * x)) - 1.f; }

__device__ __forceinline__ bf16x8 cvt8(const float* p) {
    const float4 v0 = *(const float4*)p;
    const float4 v1 = *(const float4*)(p + 4);
    bf16x8 a;
    a[0] = f2bf(v0.x); a[1] = f2bf(v0.y); a[2] = f2bf(v0.z); a[3] = f2bf(v0.w);
    a[4] = f2bf(v1.x); a[5] = f2bf(v1.y); a[6] = f2bf(v1.z); a[7] = f2bf(v1.w);
    return a;
}

// -------- device-coherent (MALL-level) state exchange: relaxed agent atomics --------
// Bypass the (non-coherent) per-XCD L2 entirely: no acquire/invalidate needed, and
// the L2-cached weights/x stay resident across all 1024 steps.
__device__ __forceinline__ unsigned long long ld64(const short* p) {
    return __hip_atomic_load((const unsigned long long*)p, __ATOMIC_RELAXED, __HIP_MEMORY_SCOPE_AGENT);
}
__device__ __forceinline__ bf16x8 ld16B(const short* p) {
    union { unsigned long long u[2]; bf16x8 v; } x;
    x.u[0] = ld64(p);
    x.u[1] = ld64(p + 4);
    return x.v;
}
__device__ __forceinline__ void st2(short* p, short v) {
    __hip_atomic_store((unsigned short*)p, (unsigned short)v, __ATOMIC_RELAXED, __HIP_MEMORY_SCOPE_AGENT);
}
__device__ __forceinline__ int aldi(const int* p) {
    return __hip_atomic_load(p, __ATOMIC_RELAXED, __HIP_MEMORY_SCOPE_AGENT);
}

// ---- per-WAVE flag protocol (no __syncthreads anywhere in the main loops) ----
// Flag layout per rt group: int[18 blocks][2 wvr][2 wvc]  (72 ints, padded to 128).
// flag value k  <=>  that wave has finished step k-1 AND its stores are visible
// (release store => s_waitcnt vmcnt(0) of that wave's stores precedes the flag).
// A consumer wave only reads rows of its own wvr half, so it polls exactly the
// 32 same-wvr L1 waves (16 blocks x 2 wvc) + the 4 same-wvr L2 waves.
__device__ __forceinline__ void wave_publish(int* slot, int val) {
    if ((threadIdx.x & 63) == 0)
        __hip_atomic_store(slot, val, __ATOMIC_RELEASE, __HIP_MEMORY_SCOPE_AGENT);
}
__device__ __forceinline__ void wave_wait(const int* gflags, int wvr, int tgtL1, int tgtL2) {
    const int lane = threadIdx.x & 63;
    int idx = 0, tgt = 0; bool active = false;
    if (lane < 32) {            // L1 peers: block = lane>>1, wvc = lane&1
        idx = (lane >> 1) * 4 + wvr * 2 + (lane & 1); tgt = tgtL1; active = true;
    } else if (lane < 36) {     // L2: u2 = (lane>>1)&1, wvc = lane&1
        idx = (16 + ((lane >> 1) & 1)) * 4 + wvr * 2 + (lane & 1); tgt = tgtL2; active = true;
    }
    long spins = 0;
    for (;;) {
        bool ok = !active || (aldi(gflags + idx) >= tgt);
        if (__all(ok)) break;
        if (++spins > TRIES) break;   // safety valve
        __builtin_amdgcn_s_sleep(1);
    }
    __atomic_signal_fence(__ATOMIC_ACQUIRE);
}

// ---------------- prepack (unchanged layouts) ----------------
// w1f: [ut 32][kb 18][gate 4][n 16][kk 32]  (gcol = gate*512 + ut*16 + n, k = kb*32+kk)
// w2f: [ut4 4][kb 18][gate 4][n 16][kk 32]  (gcol = gate*64 + ut4*16 + n)
__global__ void prep_kernel(const float* __restrict__ Wih1, const float* __restrict__ Whh1,
                            const float* __restrict__ Wih2, const float* __restrict__ Whh2,
                            const float* __restrict__ bih1, const float* __restrict__ bhh1,
                            const float* __restrict__ bih2, const float* __restrict__ bhh2,
                            short* __restrict__ h1g, short* __restrict__ h2g,
                            short* __restrict__ w1f, short* __restrict__ w2f,
                            float* __restrict__ bs1, float* __restrict__ bs2,
                            int* __restrict__ bar) {
    const int i0 = blockIdx.x * blockDim.x + threadIdx.x;
    const int stride = gridDim.x * blockDim.x;
    for (int i = i0; i < 1024; i += stride) bar[i] = 0;                // 8 groups x 128 ints
    for (int i = i0; i < 2 * Bn * Hn; i += stride) h1g[i] = 0;
    for (int i = i0; i < 2 * Bn * Fn; i += stride) h2g[i] = 0;
    for (int i = i0; i < 2048 * 576; i += stride) {
        int kk = i & 31, n = (i >> 5) & 15, ct = (i >> 9) & 3;
        int r = i >> 11; int kb = r % 18; int ut = r / 18;
        int gcol = ct * 512 + ut * 16 + n;
        int k = kb * 32 + kk;
        float v = (k < 64) ? Wih1[gcol * 64 + k] : Whh1[gcol * 512 + (k - 64)];
        w1f[i] = f2bf(v);
    }
    for (int i = i0; i < 256 * 576; i += stride) {
        int kk = i & 31, n = (i >> 5) & 15, ct = (i >> 9) & 3;
        int r = i >> 11; int kb = r % 18; int ut4 = r / 18;
        int gcol = ct * 64 + ut4 * 16 + n;
        int k = kb * 32 + kk;
        float v = (k < 512) ? Wih2[gcol * 512 + k] : Whh2[gcol * 64 + (k - 512)];
        w2f[i] = f2bf(v);
    }
    for (int i = i0; i < 2048; i += stride) bs1[i] = bih1[i] + bhh1[i];
    for (int i = i0; i < 256;  i += stride) bs2[i] = bih2[i] + bhh2[i];
}

// ---------------- main persistent kernel ----------------
// 144 blocks x 256 threads (4 waves), 1 block/CU, 1 wave/SIMD -> 512 unified-VGPR budget.
// Waves: wvr = wv&1 (row half: 32 rows), wvc = wv>>1 (col half: one 16-unit tile).
// Dependence targets (flag = completed iterations, per WAVE):
//   L1 iter t: same-wvr L1 waves >= t   (RAW h1(t-1) + WAR h1[(t+1)&1]),
//              same-wvr L2 waves >= t-1 (WAR on c1[t&1])
//   L2 iter t: same-wvr L1 waves >= t+1 (RAW c1(t)),
//              same-wvr L2 waves >= t   (RAW h2(t-1) + WAR h2)
// Waves never block-synchronize: each publishes its own flag with a release
// store (drains only its own vmcnt) and polls only the wave set it depends on.
__global__ __launch_bounds__(256, 1) void lstm_kernel(
    const float* __restrict__ data,
    const short* __restrict__ w1f, const float* __restrict__ bs1,
    const short* __restrict__ w2f, const float* __restrict__ bs2,
    short* __restrict__ h1g, short* __restrict__ c1g, short* __restrict__ h2g,
    float* __restrict__ out, int* __restrict__ bar) {
    const int tid = threadIdx.x;
    const int lane = tid & 63, wv = tid >> 6;
    const int n = lane & 15, q = lane >> 4;
    const int wvr = wv & 1, wvc = wv >> 1;
    const int bid = blockIdx.x;
    const f32x4 Z4 = {0.f, 0.f, 0.f, 0.f};

    if (bid < NB1) {
        // ---------------- LSTM1 ----------------
        const int rt = bid >> 4, utp = bid & 15;
        const int ut = utp * 2 + wvc;
        const int rowbase = rt * 64 + wvr * 32;
        const int ucol = ut * 16 + n;
        int* grp = bar + rt * 128;
        int* myflag = grp + utp * 4 + wvr * 2 + wvc;
        const float bi_ = bs1[ucol], bf_ = bs1[512 + ucol], bg_ = bs1[1024 + ucol], bo_ = bs1[1536 + ucol];
        const short* wbase = w1f + ut * 36864 + n * 32 + q * 8;
        const int r0 = rowbase + n, r1 = rowbase + 16 + n;

        // recurrent weights (kb 2..17) -> registers, once
        bf16x8 wr[16][4];
#pragma unroll
        for (int kb = 0; kb < 16; ++kb)
#pragma unroll
            for (int g = 0; g < 4; ++g)
                wr[kb][g] = *(const bf16x8*)(wbase + ((kb + 2) * 4 + g) * 512);

        f32x4 c1f[2]; c1f[0] = Z4; c1f[1] = Z4;

        for (int t = 0; t < Tn; ++t) {
            const short* h1r = h1g + (t & 1) * (Bn * Hn);
            short* h1w = h1g + ((t + 1) & 1) * (Bn * Hn);
            short* c1w = c1g + (t & 1) * (Bn * Hn);
            f32x4 acc[2][4];
#pragma unroll
            for (int a = 0; a < 2; ++a)
#pragma unroll
                for (int g = 0; g < 4; ++g) acc[a][g] = Z4;

            // ---- x part (kb 0,1): independent of peers -> runs BEFORE the wait,
            // its HBM/L2 latency hides under the flag spin.
            const float* x0 = data + (size_t)r0 * 65536 + t * 64;
            const float* x1 = data + (size_t)r1 * 65536 + t * 64;
#pragma unroll
            for (int kb = 0; kb < 2; ++kb) {
                const bf16x8 a0 = cvt8(x0 + kb * 32 + q * 8);
                const bf16x8 a1 = cvt8(x1 + kb * 32 + q * 8);
#pragma unroll
                for (int g = 0; g < 4; ++g) {
                    const bf16x8 b = *(const bf16x8*)(wbase + (kb * 4 + g) * 512);
                    acc[0][g] = __builtin_amdgcn_mfma_f32_16x16x32_bf16(a0, b, acc[0][g], 0, 0, 0);
                    acc[1][g] = __builtin_amdgcn_mfma_f32_16x16x32_bf16(a1, b, acc[1][g], 0, 0, 0);
                }
            }

            wave_wait(grp, wvr, t, t - 1);   // exactly the waves this wave depends on

            // ---- h part (kb 2..17): interleaved loads + MFMA (compiler pipelines)
#pragma unroll
            for (int kb = 0; kb < 16; ++kb) {
                const int k = kb * 32 + q * 8;
                const bf16x8 a0 = ld16B(h1r + r0 * 512 + k);
                const bf16x8 a1 = ld16B(h1r + r1 * 512 + k);
#pragma unroll
                for (int g = 0; g < 4; ++g) {
                    acc[0][g] = __builtin_amdgcn_mfma_f32_16x16x32_bf16(a0, wr[kb][g], acc[0][g], 0, 0, 0);
                    acc[1][g] = __builtin_amdgcn_mfma_f32_16x16x32_bf16(a1, wr[kb][g], acc[1][g], 0, 0, 0);
                }
            }

            // epilogue: C-frag col = lane&15 (unit), row = q*4 + reg
#pragma unroll
            for (int rt16 = 0; rt16 < 2; ++rt16) {
#pragma unroll
                for (int r = 0; r < 4; ++r) {
                    const float xi = acc[rt16][0][r] + bi_;
                    const float xf = acc[rt16][1][r] + bf_;
                    const float xg = acc[rt16][2][r] + bg_;
                    const float xo = acc[rt16][3][r] + bo_;
                    const float ii = sigm(xi), ff = sigm(xf), gg = tanh_(xg), oo = sigm(xo);
                    const float c = ff * c1f[rt16][r] + ii * gg;
                    c1f[rt16][r] = c;
                    const float h = oo * tanh_(c);
                    const int row = rowbase + rt16 * 16 + q * 4 + r;
                    st2(h1w + row * 512 + ucol, f2bf(h));
                    st2(c1w + row * 512 + ucol, f2bf(c));
                }
            }
            wave_publish(myflag, t + 1);   // release: drains THIS wave's stores only
        }
    } else {
        // ---------------- LSTM2 ----------------
        const int b2 = bid - NB1;
        const int rt2 = b2 >> 1, u2 = b2 & 1;
        const int ut4 = u2 * 2 + wvc;
        const int rowbase = rt2 * 64 + wvr * 32;
        const int ucol = ut4 * 16 + n;
        int* grp = bar + rt2 * 128;
        int* myflag = grp + (16 + u2) * 4 + wvr * 2 + wvc;
        const float bi_ = bs2[ucol], bf_ = bs2[64 + ucol], bg_ = bs2[128 + ucol], bo_ = bs2[192 + ucol];
        const short* wbase = w2f + ut4 * 36864 + n * 32 + q * 8;
        const int r0 = rowbase + n, r1 = rowbase + 16 + n;

        // c1-part weights (kb 0..15) -> registers
        bf16x8 wr[16][4];
#pragma unroll
        for (int kb = 0; kb < 16; ++kb)
#pragma unroll
            for (int g = 0; g < 4; ++g)
                wr[kb][g] = *(const bf16x8*)(wbase + (kb * 4 + g) * 512);

        f32x4 c2f[2]; c2f[0] = Z4; c2f[1] = Z4;

        for (int t = 0; t < Tn; ++t) {
            wave_wait(grp, wvr, t + 1, t);   // c1(t) from L1; h2(t-1)+WAR from pair
            const short* c1r = c1g + (t & 1) * (Bn * Hn);
            const short* h2r = h2g + (t & 1) * (Bn * Fn);
            short* h2w = h2g + ((t + 1) & 1) * (Bn * Fn);
            f32x4 acc[2][4];
#pragma unroll
            for (int a = 0; a < 2; ++a)
#pragma unroll
                for (int g = 0; g < 4; ++g) acc[a][g] = Z4;

#pragma unroll
            for (int kb = 0; kb < 16; ++kb) {
                const int k = kb * 32 + q * 8;
                const bf16x8 a0 = ld16B(c1r + r0 * 512 + k);
                const bf16x8 a1 = ld16B(c1r + r1 * 512 + k);
#pragma unroll
                for (int g = 0; g < 4; ++g) {
                    acc[0][g] = __builtin_amdgcn_mfma_f32_16x16x32_bf16(a0, wr[kb][g], acc[0][g], 0, 0, 0);
                    acc[1][g] = __builtin_amdgcn_mfma_f32_16x16x32_bf16(a1, wr[kb][g], acc[1][g], 0, 0, 0);
                }
            }
#pragma unroll
            for (int kb = 16; kb < 18; ++kb) {
                const int k = (kb - 16) * 32 + q * 8;
                const bf16x8 a0 = ld16B(h2r + r0 * 64 + k);
                const bf16x8 a1 = ld16B(h2r + r1 * 64 + k);
#pragma unroll
                for (int g = 0; g < 4; ++g) {
                    const bf16x8 b = *(const bf16x8*)(wbase + (kb * 4 + g) * 512);
                    acc[0][g] = __builtin_amdgcn_mfma_f32_16x16x32_bf16(a0, b, acc[0][g], 0, 0, 0);
                    acc[1][g] = __builtin_amdgcn_mfma_f32_16x16x32_bf16(a1, b, acc[1][g], 0, 0, 0);
                }
            }
#pragma unroll
            for (int rt16 = 0; rt16 < 2; ++rt16) {
#pragma unroll
                for (int r = 0; r < 4; ++r) {
                    const float xi = acc[rt16][0][r] + bi_;
                    const float xf = acc[rt16][1][r] + bf_;
                    const float xg = acc[rt16][2][r] + bg_;
                    const float xo = acc[rt16][3][r] + bo_;
                    const float ii = sigm(xi), ff = sigm(xf), gg = tanh_(xg), oo = sigm(xo);
                    const float c = ff * c2f[rt16][r] + ii * gg;
                    c2f[rt16][r] = c;
                    const float h = oo * tanh_(c);
                    const int row = rowbase + rt16 * 16 + q * 4 + r;
                    out[(size_t)row * 65536 + (size_t)t * 64 + ucol] = c;  // output is c2
                    st2(h2w + row * 64 + ucol, f2bf(h));
                }
            }
            wave_publish(myflag, t + 1);   // publishes h2(t) + done reading c1(t)
        }
    }
}

extern "C" void kernel_launch(void* const* d_in, const int* in_sizes, int n_in,
                              void* d_out, int out_size, void* d_ws, size_t ws_size,
                              hipStream_t stream) {
    const float* data = (const float*)d_in[0];
    const float* Wih1 = (const float*)d_in[1];
    const float* Whh1 = (const float*)d_in[2];
    const float* bih1 = (const float*)d_in[3];
    const float* bhh1 = (const float*)d_in[4];
    const float* Wih2 = (const float*)d_in[5];
    const float* Whh2 = (const float*)d_in[6];
    const float* bih2 = (const float*)d_in[7];
    const float* bhh2 = (const float*)d_in[8];
    float* out = (float*)d_out;

    char* w = (char*)d_ws;
    short* h1g = (short*)(w + 0);          // 2 * 512*512*2 = 1,048,576
    short* c1g = (short*)(w + 1048576);    // 1,048,576
    short* h2g = (short*)(w + 2097152);    // 2 * 512*64*2 = 131,072
    short* w2f = (short*)(w + 2228224);    // 256*576*2 = 294,912
    short* w1f = (short*)(w + 2523136);    // 2048*576*2 = 2,359,296
    float* bs1 = (float*)(w + 4882432);    // 8,192
    float* bs2 = (float*)(w + 4890624);    // 1,024
    int* bar  = (int*)(w + 4891648);       // 4 KB: 8 groups x 128 ints

    hipLaunchKernelGGL(prep_kernel, dim3(1024), dim3(256), 0, stream,
                       Wih1, Whh1, Wih2, Whh2, bih1, bhh1, bih2, bhh2,
                       h1g, h2g, w1f, w2f, bs1, bs2, bar);

    hipLaunchKernelGGL(lstm_kernel, dim3(NBLK), dim3(256), 0, stream,
                       data, w1f, bs1, w2f, bs2, h1g, c1g, h2g, out, bar);
}

// Round 7
// 8305.217 us; speedup vs baseline: 3.0807x; 2.6668x over previous
//
#include <hip/hip_runtime.h>

// Problem constants
#define Bn   512
#define Tn   1024
#define Fn   64
#define Hn   512
#define NB1  128                 // LSTM1 blocks: 8 rt x 16 utp
#define NB2  16                  // LSTM2 blocks: 8 rt x 2 u2
#define NBLK (NB1 + NB2)
#define GMEM 18                  // members per rt group: 16 L1 + 2 L2
#define TRIES (1L << 22)

typedef short bf16x8 __attribute__((ext_vector_type(8)));
typedef float f32x4  __attribute__((ext_vector_type(4)));

__device__ __forceinline__ short f2bf(float f) {
    union { float f; unsigned u; } v; v.f = f;
    unsigned r = (v.u + 0x7FFFu + ((v.u >> 16) & 1u)) >> 16;  // RNE
    return (short)(unsigned short)r;
}
__device__ __forceinline__ float sigm(float x) { return 1.f / (1.f + __expf(-x)); }
__device__ __forceinline__ float tanh_(float x) { return 2.f / (1.f + __expf(-2.f * x)) - 1.f; }

__device__ __forceinline__ bf16x8 cvt8(const float* p) {
    const float4 v0 = *(const float4*)p;
    const float4 v1 = *(const float4*)(p + 4);
    bf16x8 a;
    a[0] = f2bf(v0.x); a[1] = f2bf(v0.y); a[2] = f2bf(v0.z); a[3] = f2bf(v0.w);
    a[4] = f2bf(v1.x); a[5] = f2bf(v1.y); a[6] = f2bf(v1.z); a[7] = f2bf(v1.w);
    return a;
}

// -------- device-coherent exchange primitives --------
// sc0+sc1 = system scope: bypasses L1/L2, served by the memory-side cache.
// Strictly at-least-as-coherent as R3's working agent-scope atomics.
// All asm loads use hand-counted vmcnt; every s_waitcnt is followed by
// sched_barrier(0) so the compiler cannot hoist dependent code above it.
__device__ __forceinline__ void ldx16(bf16x8& d, const short* p) {
    asm volatile("global_load_dwordx4 %0, %1, off sc0 sc1" : "=v"(d) : "v"(p));
}
__device__ __forceinline__ void stx16(short* p, bf16x8 v) {
    asm volatile("global_store_dwordx4 %0, %1, off sc0 sc1" :: "v"(p), "v"(v) : "memory");
}
#define VMWAIT(N) do { \
    asm volatile("s_waitcnt vmcnt(" #N ")" ::: "memory"); \
    __builtin_amdgcn_sched_barrier(0); } while (0)

__device__ __forceinline__ int aldi(const int* p) {
    return __hip_atomic_load(p, __ATOMIC_RELAXED, __HIP_MEMORY_SCOPE_AGENT);
}

// ---- per-member flag barrier (R3 protocol, proven correct @13.4ms) ----
// flag[m] = completed iterations of member m. Arrive: drain ALL vmem (incl. the
// asm stores the compiler doesn't track), block-barrier, release-store flag.
__device__ __forceinline__ void flag_arrive(int* slot, int val) {
    asm volatile("s_waitcnt vmcnt(0)" ::: "memory");
    __builtin_amdgcn_sched_barrier(0);
    __syncthreads();
    if (threadIdx.x == 0)
        __hip_atomic_store(slot, val, __ATOMIC_RELEASE, __HIP_MEMORY_SCOPE_AGENT);
}
__device__ __forceinline__ void flag_wait(const int* flags, int tgtA, int tgtB) {
    const int lane = threadIdx.x & 63;
    const int tgt = (lane < 16) ? tgtA : tgtB;
    long spins = 0;
    for (;;) {
        bool ok = (lane >= GMEM) ||
            (aldi(flags + lane) >= tgt);
        if (__all(ok)) break;
        if (++spins > TRIES) break;   // safety valve
        __builtin_amdgcn_s_sleep(1);
    }
    __atomic_signal_fence(__ATOMIC_ACQUIRE);
    __builtin_amdgcn_sched_barrier(0);
}

// ---------------- prepack (unchanged layouts) ----------------
// w1f: [ut 32][kb 18][gate 4][n 16][kk 32]  (gcol = gate*512 + ut*16 + n, k = kb*32+kk)
// w2f: [ut4 4][kb 18][gate 4][n 16][kk 32]  (gcol = gate*64 + ut4*16 + n)
__global__ void prep_kernel(const float* __restrict__ Wih1, const float* __restrict__ Whh1,
                            const float* __restrict__ Wih2, const float* __restrict__ Whh2,
                            const float* __restrict__ bih1, const float* __restrict__ bhh1,
                            const float* __restrict__ bih2, const float* __restrict__ bhh2,
                            short* __restrict__ h1g, short* __restrict__ h2g,
                            short* __restrict__ w1f, short* __restrict__ w2f,
                            float* __restrict__ bs1, float* __restrict__ bs2,
                            int* __restrict__ bar) {
    const int i0 = blockIdx.x * blockDim.x + threadIdx.x;
    const int stride = gridDim.x * blockDim.x;
    for (int i = i0; i < 1024; i += stride) bar[i] = 0;                // 8 groups x 32 ints (padded)
    for (int i = i0; i < 2 * Bn * Hn; i += stride) h1g[i] = 0;
    for (int i = i0; i < 2 * Bn * Fn; i += stride) h2g[i] = 0;
    for (int i = i0; i < 2048 * 576; i += stride) {
        int kk = i & 31, n = (i >> 5) & 15, ct = (i >> 9) & 3;
        int r = i >> 11; int kb = r % 18; int ut = r / 18;
        int gcol = ct * 512 + ut * 16 + n;
        int k = kb * 32 + kk;
        float v = (k < 64) ? Wih1[gcol * 64 + k] : Whh1[gcol * 512 + (k - 64)];
        w1f[i] = f2bf(v);
    }
    for (int i = i0; i < 256 * 576; i += stride) {
        int kk = i & 31, n = (i >> 5) & 15, ct = (i >> 9) & 3;
        int r = i >> 11; int kb = r % 18; int ut4 = r / 18;
        int gcol = ct * 64 + ut4 * 16 + n;
        int k = kb * 32 + kk;
        float v = (k < 512) ? Wih2[gcol * 512 + k] : Whh2[gcol * 64 + (k - 512)];
        w2f[i] = f2bf(v);
    }
    for (int i = i0; i < 2048; i += stride) bs1[i] = bih1[i] + bhh1[i];
    for (int i = i0; i < 256;  i += stride) bs2[i] = bih2[i] + bhh2[i];
}

// ---------------- main persistent kernel ----------------
// 144 blocks x 256 threads. R3 flag protocol + 3 fabric-op reductions:
//  (1) 16B sc0sc1 loads (vs 2x8B atomics), (2) block-LDS staging de-dups the
//  wvc-duplicated reads, (3) LDS-transpose epilogue -> 16B stores (vs 16x2B).
// LDS map (shorts): smem[0..32768) = 64x512 staged slice (XOR-swizzled:
//   elem(row,col16) at row*512 + (col16^(row&7))*8), smem[32768..34816) = h tile
//   64x32, smem[34816..36864) = c tile 64x32. Dynamic LDS = 73728 B.
// Staging chunk c (0..4095): global elems gsrc + c*8 (row=c>>6, col16=c&63).
// vmcnt batching: issue 16 (+4 for L2's h2) loads, VMWAIT(8) -> oldest done
// (newest 8 = batch1 regardless of prior outstanding; vmcnt completes in-order).
__global__ __launch_bounds__(256, 1) void lstm_kernel(
    const float* __restrict__ data,
    const short* __restrict__ w1f, const float* __restrict__ bs1,
    const short* __restrict__ w2f, const float* __restrict__ bs2,
    short* __restrict__ h1g, short* __restrict__ c1g, short* __restrict__ h2g,
    float* __restrict__ out, int* __restrict__ bar) {
    extern __shared__ short smem[];
    const int tid = threadIdx.x;
    const int lane = tid & 63, wv = tid >> 6;
    const int n = lane & 15, q = lane >> 4;
    const int wvr = wv & 1, wvc = wv >> 1;
    const int bid = blockIdx.x;
    const f32x4 Z4 = {0.f, 0.f, 0.f, 0.f};
    short* htile = smem + 32768;
    short* ctile = smem + 34816;

    if (bid < NB1) {
        // ---------------- LSTM1 ----------------
        const int rt = bid >> 4, utp = bid & 15;
        const int ut = utp * 2 + wvc;
        const int rowbase = rt * 64 + wvr * 32;
        const int ucol = ut * 16 + n;
        int* grp = bar + rt * 32;
        const float bi_ = bs1[ucol], bf_ = bs1[512 + ucol], bg_ = bs1[1024 + ucol], bo_ = bs1[1536 + ucol];
        const short* wbase = w1f + ut * 36864 + n * 32 + q * 8;
        const int r0 = rowbase + n, r1 = rowbase + 16 + n;
        const int lr0 = wvr * 32 + n, lr1 = lr0 + 16, sw = n & 7;

        // recurrent weights (kb 2..17) -> registers, once
        bf16x8 wr[16][4];
#pragma unroll
        for (int kb = 0; kb < 16; ++kb)
#pragma unroll
            for (int g = 0; g < 4; ++g)
                wr[kb][g] = *(const bf16x8*)(wbase + ((kb + 2) * 4 + g) * 512);

        f32x4 c1f[2]; c1f[0] = Z4; c1f[1] = Z4;

        for (int t = 0; t < Tn; ++t) {
            const short* h1r = h1g + (t & 1) * (Bn * Hn);
            short* h1w = h1g + ((t + 1) & 1) * (Bn * Hn);
            short* c1w = c1g + (t & 1) * (Bn * Hn);
            f32x4 acc[2][4];
#pragma unroll
            for (int a = 0; a < 2; ++a)
#pragma unroll
                for (int g = 0; g < 4; ++g) acc[a][g] = Z4;

            // x part (kb 0,1): cached loads, before the wait (hides under spin)
            const float* x0 = data + (size_t)r0 * 65536 + t * 64;
            const float* x1 = data + (size_t)r1 * 65536 + t * 64;
#pragma unroll
            for (int kb = 0; kb < 2; ++kb) {
                const bf16x8 a0 = cvt8(x0 + kb * 32 + q * 8);
                const bf16x8 a1 = cvt8(x1 + kb * 32 + q * 8);
#pragma unroll
                for (int g = 0; g < 4; ++g) {
                    const bf16x8 b = *(const bf16x8*)(wbase + (kb * 4 + g) * 512);
                    acc[0][g] = __builtin_amdgcn_mfma_f32_16x16x32_bf16(a0, b, acc[0][g], 0, 0, 0);
                    acc[1][g] = __builtin_amdgcn_mfma_f32_16x16x32_bf16(a1, b, acc[1][g], 0, 0, 0);
                }
            }

            flag_wait(grp, t, t - 1);   // peers' h1(t-1); L2 done with c1[t&1]

            // ---- stage the 64x512 h slice into LDS (16 chunks/thread) ----
            const short* gsrc = h1r + (size_t)rt * 32768;
            bf16x8 st[16];
            __builtin_amdgcn_sched_barrier(0);
#pragma unroll
            for (int i = 0; i < 16; ++i) {
                const int c = i * 256 + tid;
                ldx16(st[i], gsrc + c * 8);
            }
            VMWAIT(8);   // batch0 (i 0..7) complete
#pragma unroll
            for (int i = 0; i < 8; ++i) {
                const int c = i * 256 + tid; const int row = c >> 6, col = c & 63;
                *(bf16x8*)&smem[row * 512 + ((col ^ (row & 7)) * 8)] = st[i];
            }
            VMWAIT(0);   // batch1 complete
#pragma unroll
            for (int i = 8; i < 16; ++i) {
                const int c = i * 256 + tid; const int row = c >> 6, col = c & 63;
                *(bf16x8*)&smem[row * 512 + ((col ^ (row & 7)) * 8)] = st[i];
            }
            __syncthreads();

            // ---- h part (kb 0..15 over staged slice; weights in regs) ----
#pragma unroll
            for (int kb = 0; kb < 16; ++kb) {
                const bf16x8 a0 = *(const bf16x8*)&smem[lr0 * 512 + (((kb * 4 + q) ^ sw) * 8)];
                const bf16x8 a1 = *(const bf16x8*)&smem[lr1 * 512 + (((kb * 4 + q) ^ sw) * 8)];
#pragma unroll
                for (int g = 0; g < 4; ++g) {
                    acc[0][g] = __builtin_amdgcn_mfma_f32_16x16x32_bf16(a0, wr[kb][g], acc[0][g], 0, 0, 0);
                    acc[1][g] = __builtin_amdgcn_mfma_f32_16x16x32_bf16(a1, wr[kb][g], acc[1][g], 0, 0, 0);
                }
            }

            // ---- epilogue: gates -> LDS tiles (transpose) -> 16B stores ----
#pragma unroll
            for (int rt16 = 0; rt16 < 2; ++rt16) {
#pragma unroll
                for (int r = 0; r < 4; ++r) {
                    const float xi = acc[rt16][0][r] + bi_;
                    const float xf = acc[rt16][1][r] + bf_;
                    const float xg = acc[rt16][2][r] + bg_;
                    const float xo = acc[rt16][3][r] + bo_;
                    const float ii = sigm(xi), ff = sigm(xf), gg = tanh_(xg), oo = sigm(xo);
                    const float c = ff * c1f[rt16][r] + ii * gg;
                    c1f[rt16][r] = c;
                    const float h = oo * tanh_(c);
                    const int lr = wvr * 32 + rt16 * 16 + q * 4 + r;
                    const int lu = wvc * 16 + n;
                    htile[lr * 32 + lu] = f2bf(h);
                    ctile[lr * 32 + lu] = f2bf(c);
                }
            }
            __syncthreads();
            {
                const int row = tid >> 2, part = tid & 3;
                const bf16x8 hv = *(const bf16x8*)&htile[row * 32 + part * 8];
                const bf16x8 cv = *(const bf16x8*)&ctile[row * 32 + part * 8];
                short* gdst = h1w + (size_t)(rt * 64 + row) * 512 + utp * 32 + part * 8;
                short* gdc  = c1w + (size_t)(rt * 64 + row) * 512 + utp * 32 + part * 8;
                stx16(gdst, hv);
                stx16(gdc, cv);
            }
            flag_arrive(grp + utp, t + 1);   // vmcnt(0) + barrier + release flag
        }
    } else {
        // ---------------- LSTM2 ----------------
        const int b2 = bid - NB1;
        const int rt2 = b2 >> 1, u2 = b2 & 1;
        const int ut4 = u2 * 2 + wvc;
        const int rowbase = rt2 * 64 + wvr * 32;
        const int ucol = ut4 * 16 + n;
        int* grp = bar + rt2 * 32;
        const float bi_ = bs2[ucol], bf_ = bs2[64 + ucol], bg_ = bs2[128 + ucol], bo_ = bs2[192 + ucol];
        const short* wbase = w2f + ut4 * 36864 + n * 32 + q * 8;
        const int r0 = rowbase + n, r1 = rowbase + 16 + n;
        const int lr0 = wvr * 32 + n, lr1 = lr0 + 16, sw = n & 7;

        // c1-part weights (kb 0..15) + h2 tail weights -> registers
        bf16x8 wr[16][4];
#pragma unroll
        for (int kb = 0; kb < 16; ++kb)
#pragma unroll
            for (int g = 0; g < 4; ++g)
                wr[kb][g] = *(const bf16x8*)(wbase + (kb * 4 + g) * 512);
        bf16x8 wh[2][4];
#pragma unroll
        for (int kb2 = 0; kb2 < 2; ++kb2)
#pragma unroll
            for (int g = 0; g < 4; ++g)
                wh[kb2][g] = *(const bf16x8*)(wbase + ((16 + kb2) * 4 + g) * 512);

        f32x4 c2f[2]; c2f[0] = Z4; c2f[1] = Z4;

        for (int t = 0; t < Tn; ++t) {
            flag_wait(grp, t + 1, t);        // c1(t) from L1; h2(t-1)+WAR from pair
            const short* c1r = c1g + (t & 1) * (Bn * Hn);
            const short* h2r = h2g + (t & 1) * (Bn * Fn);
            short* h2w = h2g + ((t + 1) & 1) * (Bn * Fn);
            f32x4 acc[2][4];
#pragma unroll
            for (int a = 0; a < 2; ++a)
#pragma unroll
                for (int g = 0; g < 4; ++g) acc[a][g] = Z4;

            // h2 tail loads first (oldest), then stage c1 slice
            bf16x8 SH[4];
            __builtin_amdgcn_sched_barrier(0);
            ldx16(SH[0], h2r + (size_t)r0 * 64 + q * 8);
            ldx16(SH[1], h2r + (size_t)r0 * 64 + 32 + q * 8);
            ldx16(SH[2], h2r + (size_t)r1 * 64 + q * 8);
            ldx16(SH[3], h2r + (size_t)r1 * 64 + 32 + q * 8);
            const short* gsrc = c1r + (size_t)rt2 * 32768;
            bf16x8 st[16];
#pragma unroll
            for (int i = 0; i < 16; ++i) {
                const int c = i * 256 + tid;
                ldx16(st[i], gsrc + c * 8);
            }
            VMWAIT(8);   // SH + batch0 complete
#pragma unroll
            for (int i = 0; i < 8; ++i) {
                const int c = i * 256 + tid; const int row = c >> 6, col = c & 63;
                *(bf16x8*)&smem[row * 512 + ((col ^ (row & 7)) * 8)] = st[i];
            }
            VMWAIT(0);
#pragma unroll
            for (int i = 8; i < 16; ++i) {
                const int c = i * 256 + tid; const int row = c >> 6, col = c & 7 ? (c & 63) : (c & 63);
                const int col2 = c & 63;
                *(bf16x8*)&smem[row * 512 + ((col2 ^ (row & 7)) * 8)] = st[i];
            }
            __syncthreads();

#pragma unroll
            for (int kb = 0; kb < 16; ++kb) {
                const bf16x8 a0 = *(const bf16x8*)&smem[lr0 * 512 + (((kb * 4 + q) ^ sw) * 8)];
                const bf16x8 a1 = *(const bf16x8*)&smem[lr1 * 512 + (((kb * 4 + q) ^ sw) * 8)];
#pragma unroll
                for (int g = 0; g < 4; ++g) {
                    acc[0][g] = __builtin_amdgcn_mfma_f32_16x16x32_bf16(a0, wr[kb][g], acc[0][g], 0, 0, 0);
                    acc[1][g] = __builtin_amdgcn_mfma_f32_16x16x32_bf16(a1, wr[kb][g], acc[1][g], 0, 0, 0);
                }
            }
#pragma unroll
            for (int g = 0; g < 4; ++g) {
                acc[0][g] = __builtin_amdgcn_mfma_f32_16x16x32_bf16(SH[0], wh[0][g], acc[0][g], 0, 0, 0);
                acc[0][g] = __builtin_amdgcn_mfma_f32_16x16x32_bf16(SH[1], wh[1][g], acc[0][g], 0, 0, 0);
                acc[1][g] = __builtin_amdgcn_mfma_f32_16x16x32_bf16(SH[2], wh[0][g], acc[1][g], 0, 0, 0);
                acc[1][g] = __builtin_amdgcn_mfma_f32_16x16x32_bf16(SH[3], wh[1][g], acc[1][g], 0, 0, 0);
            }

            // epilogue: out (cached f32) + h2 tile -> 16B stores
#pragma unroll
            for (int rt16 = 0; rt16 < 2; ++rt16) {
#pragma unroll
                for (int r = 0; r < 4; ++r) {
                    const float xi = acc[rt16][0][r] + bi_;
                    const float xf = acc[rt16][1][r] + bf_;
                    const float xg = acc[rt16][2][r] + bg_;
                    const float xo = acc[rt16][3][r] + bo_;
                    const float ii = sigm(xi), ff = sigm(xf), gg = tanh_(xg), oo = sigm(xo);
                    const float c = ff * c2f[rt16][r] + ii * gg;
                    c2f[rt16][r] = c;
                    const float h = oo * tanh_(c);
                    const int row = rowbase + rt16 * 16 + q * 4 + r;
                    out[(size_t)row * 65536 + (size_t)t * 64 + ucol] = c;  // output is c2
                    const int lr = wvr * 32 + rt16 * 16 + q * 4 + r;
                    const int lu = wvc * 16 + n;
                    htile[lr * 32 + lu] = f2bf(h);
                }
            }
            __syncthreads();
            {
                const int row = tid >> 2, part = tid & 3;
                const bf16x8 hv = *(const bf16x8*)&htile[row * 32 + part * 8];
                short* gdst = h2w + (size_t)(rt2 * 64 + row) * 64 + u2 * 32 + part * 8;
                stx16(gdst, hv);
            }
            flag_arrive(grp + 16 + u2, t + 1);   // publishes h2(t) + done reading c1(t)
        }
    }
}

extern "C" void kernel_launch(void* const* d_in, const int* in_sizes, int n_in,
                              void* d_out, int out_size, void* d_ws, size_t ws_size,
                              hipStream_t stream) {
    const float* data = (const float*)d_in[0];
    const float* Wih1 = (const float*)d_in[1];
    const float* Whh1 = (const float*)d_in[2];
    const float* bih1 = (const float*)d_in[3];
    const float* bhh1 = (const float*)d_in[4];
    const float* Wih2 = (const float*)d_in[5];
    const float* Whh2 = (const float*)d_in[6];
    const float* bih2 = (const float*)d_in[7];
    const float* bhh2 = (const float*)d_in[8];
    float* out = (float*)d_out;

    char* w = (char*)d_ws;
    short* h1g = (short*)(w + 0);          // 2 * 512*512*2 = 1,048,576
    short* c1g = (short*)(w + 1048576);    // 1,048,576
    short* h2g = (short*)(w + 2097152);    // 2 * 512*64*2 = 131,072
    short* w2f = (short*)(w + 2228224);    // 256*576*2 = 294,912
    short* w1f = (short*)(w + 2523136);    // 2048*576*2 = 2,359,296
    float* bs1 = (float*)(w + 4882432);    // 8,192
    float* bs2 = (float*)(w + 4890624);    // 1,024
    int* bar  = (int*)(w + 4891648);       // 4 KB: 8 groups x 32 ints

    hipLaunchKernelGGL(prep_kernel, dim3(1024), dim3(256), 0, stream,
                       Wih1, Whh1, Wih2, Whh2, bih1, bhh1, bih2, bhh2,
                       h1g, h2g, w1f, w2f, bs1, bs2, bar);

    hipLaunchKernelGGL(lstm_kernel, dim3(NBLK), dim3(256), 73728, stream,
                       data, w1f, bs1, w2f, bs2, h1g, c1g, h2g, out, bar);
}

// Round 8
// 7510.707 us; speedup vs baseline: 3.4066x; 1.1058x over previous
//
#include <hip/hip_runtime.h>

// Problem constants
#define Bn   512
#define Tn   1024
#define Fn   64
#define Hn   512
#define NGRP 16                  // groups: 32 batch rows each
#define GMEM 9                   // members per group: 8 L1 + 1 L2
#define NBLK (NGRP * GMEM)       // 144 blocks
#define TRIES (1L << 22)

typedef short bf16x8 __attribute__((ext_vector_type(8)));
typedef float f32x4  __attribute__((ext_vector_type(4)));

__device__ __forceinline__ short f2bf(float f) {
    union { float f; unsigned u; } v; v.f = f;
    unsigned r = (v.u + 0x7FFFu + ((v.u >> 16) & 1u)) >> 16;  // RNE
    return (short)(unsigned short)r;
}
__device__ __forceinline__ float sigm(float x) { return 1.f / (1.f + __expf(-x)); }
__device__ __forceinline__ float tanh_(float x) { return 2.f / (1.f + __expf(-2.f * x)) - 1.f; }

__device__ __forceinline__ bf16x8 cvt8(const float* p) {
    const float4 v0 = *(const float4*)p;
    const float4 v1 = *(const float4*)(p + 4);
    bf16x8 a;
    a[0] = f2bf(v0.x); a[1] = f2bf(v0.y); a[2] = f2bf(v0.z); a[3] = f2bf(v0.w);
    a[4] = f2bf(v1.x); a[5] = f2bf(v1.y); a[6] = f2bf(v1.z); a[7] = f2bf(v1.w);
    return a;
}

// -------- device-coherent exchange primitives (proven in R7) --------
__device__ __forceinline__ void ldx16(bf16x8& d, const short* p) {
    asm volatile("global_load_dwordx4 %0, %1, off sc0 sc1" : "=v"(d) : "v"(p));
}
__device__ __forceinline__ void stx16(short* p, bf16x8 v) {
    asm volatile("global_store_dwordx4 %0, %1, off sc0 sc1" :: "v"(p), "v"(v) : "memory");
}
#define VMWAIT(N) do { \
    asm volatile("s_waitcnt vmcnt(" #N ")" ::: "memory"); \
    __builtin_amdgcn_sched_barrier(0); } while (0)

__device__ __forceinline__ int aldi(const int* p) {
    return __hip_atomic_load(p, __ATOMIC_RELAXED, __HIP_MEMORY_SCOPE_AGENT);
}

// ---- per-member flag barrier (R3/R7 protocol, proven) ----
// flag[m] = completed iterations of member m. Arrive: drain ALL vmem (incl. the
// asm stores the compiler doesn't track), block-barrier, release-store flag.
__device__ __forceinline__ void flag_arrive(int* slot, int val) {
    asm volatile("s_waitcnt vmcnt(0)" ::: "memory");
    __builtin_amdgcn_sched_barrier(0);
    __syncthreads();
    if (threadIdx.x == 0)
        __hip_atomic_store(slot, val, __ATOMIC_RELEASE, __HIP_MEMORY_SCOPE_AGENT);
}
// lanes 0..7 wait for the 8 L1 flags >= tgtA; lane 8 waits for the L2 flag >= tgtB
__device__ __forceinline__ void flag_wait(const int* flags, int tgtA, int tgtB) {
    const int lane = threadIdx.x & 63;
    const int tgt = (lane < 8) ? tgtA : tgtB;
    long spins = 0;
    for (;;) {
        bool ok = (lane >= GMEM) || (aldi(flags + lane) >= tgt);
        if (__all(ok)) break;
        if (++spins > TRIES) break;   // safety valve
        __builtin_amdgcn_s_sleep(1);
    }
    __atomic_signal_fence(__ATOMIC_ACQUIRE);
    __builtin_amdgcn_sched_barrier(0);
}

// ---------------- prepack (unchanged layouts) ----------------
// w1f: [ut 32][kb 18][gate 4][n 16][kk 32]  (gcol = gate*512 + ut*16 + n, k = kb*32+kk)
// w2f: [ut4 4][kb 18][gate 4][n 16][kk 32]  (gcol = gate*64 + ut4*16 + n)
__global__ void prep_kernel(const float* __restrict__ Wih1, const float* __restrict__ Whh1,
                            const float* __restrict__ Wih2, const float* __restrict__ Whh2,
                            const float* __restrict__ bih1, const float* __restrict__ bhh1,
                            const float* __restrict__ bih2, const float* __restrict__ bhh2,
                            short* __restrict__ h1g, short* __restrict__ h2g,
                            short* __restrict__ w1f, short* __restrict__ w2f,
                            float* __restrict__ bs1, float* __restrict__ bs2,
                            int* __restrict__ bar) {
    const int i0 = blockIdx.x * blockDim.x + threadIdx.x;
    const int stride = gridDim.x * blockDim.x;
    for (int i = i0; i < 1024; i += stride) bar[i] = 0;                // 16 groups x 32 ints
    for (int i = i0; i < 2 * Bn * Hn; i += stride) h1g[i] = 0;
    for (int i = i0; i < 2 * Bn * Fn; i += stride) h2g[i] = 0;
    for (int i = i0; i < 2048 * 576; i += stride) {
        int kk = i & 31, n = (i >> 5) & 15, ct = (i >> 9) & 3;
        int r = i >> 11; int kb = r % 18; int ut = r / 18;
        int gcol = ct * 512 + ut * 16 + n;
        int k = kb * 32 + kk;
        float v = (k < 64) ? Wih1[gcol * 64 + k] : Whh1[gcol * 512 + (k - 64)];
        w1f[i] = f2bf(v);
    }
    for (int i = i0; i < 256 * 576; i += stride) {
        int kk = i & 31, n = (i >> 5) & 15, ct = (i >> 9) & 3;
        int r = i >> 11; int kb = r % 18; int ut4 = r / 18;
        int gcol = ct * 64 + ut4 * 16 + n;
        int k = kb * 32 + kk;
        float v = (k < 512) ? Wih2[gcol * 512 + k] : Whh2[gcol * 64 + (k - 512)];
        w2f[i] = f2bf(v);
    }
    for (int i = i0; i < 2048; i += stride) bs1[i] = bih1[i] + bhh1[i];
    for (int i = i0; i < 256;  i += stride) bs2[i] = bih2[i] + bhh2[i];
}

// ---------------- main persistent kernel ----------------
// 144 blocks x 256 threads (4 waves: wvc = wave = column tile). 16 groups x 32
// batch rows. Per group: 8 L1 blocks (64 units each) + 1 L2 block (all 64 units;
// h2 is block-INTERNAL in LDS parity tiles -> zero fabric traffic for h2).
// Fabric ops/step halved vs R7: each block stages a 32x512 slice (8 chunks/thr).
// LDS (shorts): [0..16384) staged slice 32x512, XOR-swizzled rows
//   (elem(row,col16) at row*512 + (col16 ^ (row&7))*8);
//   [16384..18432) htile/h2-parity0 (32x64); [18432..20480) ctile/h2-parity1.
// Flag targets (flag k <=> member finished step k-1):
//   L1@t: L1 flags >= t (RAW h1(t-1) + WAR), L2 flag >= t-1 (WAR on c1[t&1])
//   L2@t: L1 flags >= t+1 (RAW c1(t)), own flag >= t (trivial)
__global__ __launch_bounds__(256, 1) void lstm_kernel(
    const float* __restrict__ data,
    const short* __restrict__ w1f, const float* __restrict__ bs1,
    const short* __restrict__ w2f, const float* __restrict__ bs2,
    short* __restrict__ h1g, short* __restrict__ c1g,
    float* __restrict__ out, int* __restrict__ bar) {
    extern __shared__ short smem[];
    const int tid = threadIdx.x;
    const int lane = tid & 63, wv = tid >> 6;
    const int n = lane & 15, q = lane >> 4;
    const int wvc = wv;                      // 4 column tiles per block
    const int bid = blockIdx.x;
    const int rt = bid / GMEM, role = bid % GMEM;
    const f32x4 Z4 = {0.f, 0.f, 0.f, 0.f};
    const int rowbase = rt * 32;
    int* grp = bar + rt * 32;
    short* tile0 = smem + 16384;             // htile (L1) / h2 parity 0 (L2)
    short* tile1 = smem + 18432;             // ctile (L1) / h2 parity 1 (L2)
    const int r0 = rowbase + n, r1 = rowbase + 16 + n;
    const int lr0 = n, lr1 = n + 16, sw = n & 7;

    if (role < 8) {
        // ---------------- LSTM1 ----------------
        const int ut = role * 4 + wvc;       // global 16-unit tile index
        const int ucol = ut * 16 + n;
        const float bi_ = bs1[ucol], bf_ = bs1[512 + ucol], bg_ = bs1[1024 + ucol], bo_ = bs1[1536 + ucol];
        const short* wbase = w1f + ut * 36864 + n * 32 + q * 8;

        // recurrent weights (kb 2..17) -> registers, once
        bf16x8 wr[16][4];
#pragma unroll
        for (int kb = 0; kb < 16; ++kb)
#pragma unroll
            for (int g = 0; g < 4; ++g)
                wr[kb][g] = *(const bf16x8*)(wbase + ((kb + 2) * 4 + g) * 512);

        f32x4 c1f[2]; c1f[0] = Z4; c1f[1] = Z4;

        for (int t = 0; t < Tn; ++t) {
            const short* h1r = h1g + (t & 1) * (Bn * Hn);
            short* h1w = h1g + ((t + 1) & 1) * (Bn * Hn);
            short* c1w = c1g + (t & 1) * (Bn * Hn);
            f32x4 acc[2][4];
#pragma unroll
            for (int a = 0; a < 2; ++a)
#pragma unroll
                for (int g = 0; g < 4; ++g) acc[a][g] = Z4;

            // x part (kb 0,1): cached loads, before the wait (hides under spin)
            const float* x0 = data + (size_t)r0 * 65536 + t * 64;
            const float* x1 = data + (size_t)r1 * 65536 + t * 64;
#pragma unroll
            for (int kb = 0; kb < 2; ++kb) {
                const bf16x8 a0 = cvt8(x0 + kb * 32 + q * 8);
                const bf16x8 a1 = cvt8(x1 + kb * 32 + q * 8);
#pragma unroll
                for (int g = 0; g < 4; ++g) {
                    const bf16x8 b = *(const bf16x8*)(wbase + (kb * 4 + g) * 512);
                    acc[0][g] = __builtin_amdgcn_mfma_f32_16x16x32_bf16(a0, b, acc[0][g], 0, 0, 0);
                    acc[1][g] = __builtin_amdgcn_mfma_f32_16x16x32_bf16(a1, b, acc[1][g], 0, 0, 0);
                }
            }

            flag_wait(grp, t, t - 1);   // peers' h1(t-1); L2 done with c1[t&1]

            // ---- stage the group's 32x512 h slice into LDS (8 chunks/thread) ----
            const short* gsrc = h1r + (size_t)rt * 16384;
            bf16x8 st[8];
            __builtin_amdgcn_sched_barrier(0);
#pragma unroll
            for (int i = 0; i < 8; ++i) ldx16(st[i], gsrc + (i * 256 + tid) * 8);
            VMWAIT(4);   // oldest 4 complete
#pragma unroll
            for (int i = 0; i < 4; ++i) {
                const int c = i * 256 + tid; const int row = c >> 6, col = c & 63;
                *(bf16x8*)&smem[row * 512 + ((col ^ (row & 7)) * 8)] = st[i];
            }
            VMWAIT(0);
#pragma unroll
            for (int i = 4; i < 8; ++i) {
                const int c = i * 256 + tid; const int row = c >> 6, col = c & 63;
                *(bf16x8*)&smem[row * 512 + ((col ^ (row & 7)) * 8)] = st[i];
            }
            __syncthreads();

            // ---- h part (kb 0..15 over staged slice; weights in regs) ----
#pragma unroll
            for (int kb = 0; kb < 16; ++kb) {
                const bf16x8 a0 = *(const bf16x8*)&smem[lr0 * 512 + (((kb * 4 + q) ^ sw) * 8)];
                const bf16x8 a1 = *(const bf16x8*)&smem[lr1 * 512 + (((kb * 4 + q) ^ sw) * 8)];
#pragma unroll
                for (int g = 0; g < 4; ++g) {
                    acc[0][g] = __builtin_amdgcn_mfma_f32_16x16x32_bf16(a0, wr[kb][g], acc[0][g], 0, 0, 0);
                    acc[1][g] = __builtin_amdgcn_mfma_f32_16x16x32_bf16(a1, wr[kb][g], acc[1][g], 0, 0, 0);
                }
            }

            // ---- epilogue: gates -> LDS tiles (transpose) -> 16B fabric stores ----
#pragma unroll
            for (int rt16 = 0; rt16 < 2; ++rt16) {
#pragma unroll
                for (int r = 0; r < 4; ++r) {
                    const float xi = acc[rt16][0][r] + bi_;
                    const float xf = acc[rt16][1][r] + bf_;
                    const float xg = acc[rt16][2][r] + bg_;
                    const float xo = acc[rt16][3][r] + bo_;
                    const float ii = sigm(xi), ff = sigm(xf), gg = tanh_(xg), oo = sigm(xo);
                    const float c = ff * c1f[rt16][r] + ii * gg;
                    c1f[rt16][r] = c;
                    const float h = oo * tanh_(c);
                    const int lr = rt16 * 16 + q * 4 + r;      // 0..31
                    const int lu = wvc * 16 + n;               // 0..63
                    tile0[lr * 64 + lu] = f2bf(h);
                    tile1[lr * 64 + lu] = f2bf(c);
                }
            }
            __syncthreads();
            {
                const int row = tid >> 3, part = tid & 7;
                const bf16x8 hv = *(const bf16x8*)&tile0[row * 64 + part * 8];
                const bf16x8 cv = *(const bf16x8*)&tile1[row * 64 + part * 8];
                short* gdst = h1w + (size_t)(rowbase + row) * 512 + role * 64 + part * 8;
                short* gdc  = c1w + (size_t)(rowbase + row) * 512 + role * 64 + part * 8;
                stx16(gdst, hv);
                stx16(gdc, cv);
            }
            flag_arrive(grp + role, t + 1);   // vmcnt(0) + barrier + release flag
        }
    } else {
        // ---------------- LSTM2 (one block per group; h2 internal in LDS) ----------------
        const int ut4 = wvc;                 // 4 tiles cover all 64 units
        const int ucol = ut4 * 16 + n;
        const float bi_ = bs2[ucol], bf_ = bs2[64 + ucol], bg_ = bs2[128 + ucol], bo_ = bs2[192 + ucol];
        const short* wbase = w2f + ut4 * 36864 + n * 32 + q * 8;

        // c1-part weights (kb 0..15) + h2 tail weights (kb 16,17) -> registers
        bf16x8 wr[16][4];
#pragma unroll
        for (int kb = 0; kb < 16; ++kb)
#pragma unroll
            for (int g = 0; g < 4; ++g)
                wr[kb][g] = *(const bf16x8*)(wbase + (kb * 4 + g) * 512);
        bf16x8 wh[2][4];
#pragma unroll
        for (int kb2 = 0; kb2 < 2; ++kb2)
#pragma unroll
            for (int g = 0; g < 4; ++g)
                wh[kb2][g] = *(const bf16x8*)(wbase + ((16 + kb2) * 4 + g) * 512);

        // zero both h2 parity tiles (h2(-1) = 0)
        for (int i = tid; i < 2048; i += 256) { tile0[i] = 0; tile1[i] = 0; }
        __syncthreads();

        f32x4 c2f[2]; c2f[0] = Z4; c2f[1] = Z4;

        for (int t = 0; t < Tn; ++t) {
            flag_wait(grp, t + 1, t);        // c1(t) from L1 (own flag trivially >= t)
            const short* c1r = c1g + (t & 1) * (Bn * Hn);
            const short* h2rd = (t & 1) ? tile1 : tile0;
            short* h2wr = (t & 1) ? tile0 : tile1;
            f32x4 acc[2][4];
#pragma unroll
            for (int a = 0; a < 2; ++a)
#pragma unroll
                for (int g = 0; g < 4; ++g) acc[a][g] = Z4;

            // ---- stage the group's 32x512 c1 slice ----
            const short* gsrc = c1r + (size_t)rt * 16384;
            bf16x8 st[8];
            __builtin_amdgcn_sched_barrier(0);
#pragma unroll
            for (int i = 0; i < 8; ++i) ldx16(st[i], gsrc + (i * 256 + tid) * 8);
            VMWAIT(4);
#pragma unroll
            for (int i = 0; i < 4; ++i) {
                const int c = i * 256 + tid; const int row = c >> 6, col = c & 63;
                *(bf16x8*)&smem[row * 512 + ((col ^ (row & 7)) * 8)] = st[i];
            }
            VMWAIT(0);
#pragma unroll
            for (int i = 4; i < 8; ++i) {
                const int c = i * 256 + tid; const int row = c >> 6, col = c & 63;
                *(bf16x8*)&smem[row * 512 + ((col ^ (row & 7)) * 8)] = st[i];
            }
            __syncthreads();

            // ---- c1 part (staged slice) ----
#pragma unroll
            for (int kb = 0; kb < 16; ++kb) {
                const bf16x8 a0 = *(const bf16x8*)&smem[lr0 * 512 + (((kb * 4 + q) ^ sw) * 8)];
                const bf16x8 a1 = *(const bf16x8*)&smem[lr1 * 512 + (((kb * 4 + q) ^ sw) * 8)];
#pragma unroll
                for (int g = 0; g < 4; ++g) {
                    acc[0][g] = __builtin_amdgcn_mfma_f32_16x16x32_bf16(a0, wr[kb][g], acc[0][g], 0, 0, 0);
                    acc[1][g] = __builtin_amdgcn_mfma_f32_16x16x32_bf16(a1, wr[kb][g], acc[1][g], 0, 0, 0);
                }
            }
            // ---- h2 part (LDS parity tile; swizzled [row][col16^(row&7)]) ----
#pragma unroll
            for (int kb2 = 0; kb2 < 2; ++kb2) {
                const bf16x8 a0 = *(const bf16x8*)&h2rd[lr0 * 64 + (((kb2 * 4 + q) ^ sw) * 8)];
                const bf16x8 a1 = *(const bf16x8*)&h2rd[lr1 * 64 + (((kb2 * 4 + q) ^ sw) * 8)];
#pragma unroll
                for (int g = 0; g < 4; ++g) {
                    acc[0][g] = __builtin_amdgcn_mfma_f32_16x16x32_bf16(a0, wh[kb2][g], acc[0][g], 0, 0, 0);
                    acc[1][g] = __builtin_amdgcn_mfma_f32_16x16x32_bf16(a1, wh[kb2][g], acc[1][g], 0, 0, 0);
                }
            }

            // ---- epilogue: out (cached f32) + h2 -> next parity tile ----
#pragma unroll
            for (int rt16 = 0; rt16 < 2; ++rt16) {
#pragma unroll
                for (int r = 0; r < 4; ++r) {
                    const float xi = acc[rt16][0][r] + bi_;
                    const float xf = acc[rt16][1][r] + bf_;
                    const float xg = acc[rt16][2][r] + bg_;
                    const float xo = acc[rt16][3][r] + bo_;
                    const float ii = sigm(xi), ff = sigm(xf), gg = tanh_(xg), oo = sigm(xo);
                    const float c = ff * c2f[rt16][r] + ii * gg;
                    c2f[rt16][r] = c;
                    const float h = oo * tanh_(c);
                    const int lr = rt16 * 16 + q * 4 + r;       // 0..31
                    const int lu = wvc * 16 + n;                // 0..63
                    out[(size_t)(rowbase + lr) * 65536 + (size_t)t * 64 + ucol] = c;  // output is c2
                    h2wr[lr * 64 + (((lu >> 3) ^ (lr & 7)) * 8) + (lu & 7)] = f2bf(h);
                }
            }
            flag_arrive(grp + 8, t + 1);   // also the barrier protecting h2 parity reuse
        }
    }
}

extern "C" void kernel_launch(void* const* d_in, const int* in_sizes, int n_in,
                              void* d_out, int out_size, void* d_ws, size_t ws_size,
                              hipStream_t stream) {
    const float* data = (const float*)d_in[0];
    const float* Wih1 = (const float*)d_in[1];
    const float* Whh1 = (const float*)d_in[2];
    const float* bih1 = (const float*)d_in[3];
    const float* bhh1 = (const float*)d_in[4];
    const float* Wih2 = (const float*)d_in[5];
    const float* Whh2 = (const float*)d_in[6];
    const float* bih2 = (const float*)d_in[7];
    const float* bhh2 = (const float*)d_in[8];
    float* out = (float*)d_out;

    char* w = (char*)d_ws;
    short* h1g = (short*)(w + 0);          // 2 * 512*512*2 = 1,048,576
    short* c1g = (short*)(w + 1048576);    // 1,048,576
    short* h2g = (short*)(w + 2097152);    // 131,072 (unused by lstm_kernel now)
    short* w2f = (short*)(w + 2228224);    // 256*576*2 = 294,912
    short* w1f = (short*)(w + 2523136);    // 2048*576*2 = 2,359,296
    float* bs1 = (float*)(w + 4882432);    // 8,192
    float* bs2 = (float*)(w + 4890624);    // 1,024
    int* bar  = (int*)(w + 4891648);       // 4 KB: 16 groups x 32 ints

    hipLaunchKernelGGL(prep_kernel, dim3(1024), dim3(256), 0, stream,
                       Wih1, Whh1, Wih2, Whh2, bih1, bhh1, bih2, bhh2,
                       h1g, h2g, w1f, w2f, bs1, bs2, bar);

    hipLaunchKernelGGL(lstm_kernel, dim3(NBLK), dim3(256), 40960, stream,
                       data, w1f, bs1, w2f, bs2, h1g, c1g, out, bar);
}